// Round 2
// baseline (196.880 us; speedup 1.0000x reference)
//
#include <hip/hip_runtime.h>
#include <math.h>

#define BN_EPS 1e-5f

__device__ __forceinline__ float max3f(float a, float b, float c) {
    return fmaxf(fmaxf(a, b), c);
}
__device__ __forceinline__ int clampi(int v, int lo, int hi) {
    return v < lo ? lo : (v > hi ? hi : v);
}

// One block per (b,c) plane. 256 threads.
// LDS plane: x_tem (later gate) at [row+6][col+8], zero halo for conv boundary.
__global__ __launch_bounds__(256)
void mra_fused(const float* __restrict__ x,
               const float* __restrict__ wh1,
               const float* __restrict__ wv1,
               const float* __restrict__ wh2,
               const float* __restrict__ wv2,
               const float* __restrict__ bng,
               const float* __restrict__ bnb,
               const float* __restrict__ bnm,
               const float* __restrict__ bnv,
               float* __restrict__ out)
{
    __shared__ __align__(16) float sxp[76][84];

    const int plane = blockIdx.x;       // b*256 + c
    const int c     = plane & 255;
    const int tid   = threadIdx.x;
    const float* __restrict__ xp = x   + (size_t)plane * (192 * 192);
    float* __restrict__       op = out + (size_t)plane * (192 * 192);

    // ---- zero LDS (halo must be 0 for conv boundary) ----
    for (int i = tid; i < 76 * 84; i += 256) ((float*)sxp)[i] = 0.0f;
    __syncthreads();

    // ---- Phase A: x_tem = blurpool4(maxpool3x3(x)), stride 3 -> 64x64 ----
    // thread: column q = tid&63, wave wv = tid>>6 handles rows 16*wv..16*wv+15
    {
        const int q  = tid & 63;
        const int wv = tid >> 6;
        const float fw[4] = {0.125f, 0.375f, 0.375f, 0.125f};  // [1,3,3,1]/8

        int colc[6];
        #pragma unroll
        for (int k = 0; k < 6; ++k) colc[k] = clampi(3 * q - 2 + k, 0, 191);

        #pragma unroll 1
        for (int t = 0; t < 4; ++t) {
            const int pq = 16 * wv + 4 * t;   // quad of 4 output rows
            float hm[15][4];                  // horizontal 3-max per source row
            #pragma unroll
            for (int j = 0; j < 15; ++j) {
                const int rr = clampi(3 * pq - 2 + j, 0, 191);
                const float* rowp = xp + rr * 192;
                float mm[6];
                #pragma unroll
                for (int k = 0; k < 6; ++k) mm[k] = rowp[colc[k]];
                #pragma unroll
                for (int v = 0; v < 4; ++v) {
                    float h = max3f(mm[v], mm[v + 1], mm[v + 2]);
                    if (v == 0) {   // reflect pad col: window center col 1 when q==0
                        float hr = max3f(mm[2], mm[3], mm[4]);
                        h = (q == 0) ? hr : h;
                    }
                    hm[j][v] = h;
                }
            }
            #pragma unroll
            for (int i = 0; i < 4; ++i) {
                const int p = pq + i;
                float acc = 0.0f;
                #pragma unroll
                for (int u = 0; u < 4; ++u) {
                    #pragma unroll
                    for (int v = 0; v < 4; ++v) {
                        float mpv = max3f(hm[3 * i + u][v], hm[3 * i + u + 1][v], hm[3 * i + u + 2][v]);
                        if (i == 0 && u == 0) {  // reflect pad row when p==0
                            float mr = max3f(hm[2][v], hm[3][v], hm[4][v]);
                            mpv = (p == 0) ? mr : mpv;
                        }
                        acc += fw[u] * fw[v] * mpv;
                    }
                }
                sxp[p + 6][q + 8] = acc;
            }
        }
    }
    __syncthreads();

    // ---- Phase B: four directional 33-tap depthwise convs ----
    // thread: output row p = tid>>2, horizontal strip q0..q0+15, q0 = 16*(tid&3)
    const int p  = tid >> 2;
    const int q0 = (tid & 3) << 4;
    float acc[16];
    #pragma unroll
    for (int i = 0; i < 16; ++i) acc[i] = 0.0f;

    const float* __restrict__ wh1p = wh1 + c * 33;
    const float* __restrict__ wv1p = wv1 + c * 33;
    const float* __restrict__ wh2p = wh2 + c * 33;
    const float* __restrict__ wv2p = wv2 + c * 33;

    #pragma unroll
    for (int e = -6; e <= 6; ++e) {
        // rowbuf rb[j] = X(p+e, q0-8+j)   (LDS col index q0+j, halo gives zeros)
        float rb[32];
        const float* rowl = &sxp[p + e + 6][q0];
        #pragma unroll
        for (int j4 = 0; j4 < 8; ++j4) {
            float4 v4 = *(const float4*)(rowl + 4 * j4);
            rb[4 * j4 + 0] = v4.x; rb[4 * j4 + 1] = v4.y;
            rb[4 * j4 + 2] = v4.z; rb[4 * j4 + 3] = v4.w;
        }
        if (e >= -5 && e <= 5) {
            // x_h1: taps X(p+e, q+dw), w_h1[e+5][dw+1]
            #pragma unroll
            for (int dw = -1; dw <= 1; ++dw) {
                const float wt = wh1p[(e + 5) * 3 + dw + 1];
                #pragma unroll
                for (int i = 0; i < 16; ++i) acc[i] += wt * rb[i + dw + 8];
            }
            // x_h2: taps X(p+e, q+dw-e), w_h2[e+5][dw+1]
            #pragma unroll
            for (int dw = -1; dw <= 1; ++dw) {
                const float wt = wh2p[(e + 5) * 3 + dw + 1];
                #pragma unroll
                for (int i = 0; i < 16; ++i) acc[i] += wt * rb[i + dw - e + 8];
            }
        }
        if (e >= -1 && e <= 1) {
            // x_w1: taps X(p+e, q+dw), w_v1[e+1][dw+5]
            #pragma unroll
            for (int dw = -5; dw <= 5; ++dw) {
                const float wt = wv1p[(e + 1) * 11 + dw + 5];
                #pragma unroll
                for (int i = 0; i < 16; ++i) acc[i] += wt * rb[i + dw + 8];
            }
        }
        // x_w2: row offset e = dh-dw -> dw = dh-e; taps X(p+e, q+dh-e), w_v2[dh+1][dw+5]
        #pragma unroll
        for (int dh = -1; dh <= 1; ++dh) {
            const int dw = dh - e;
            if (dw >= -5 && dw <= 5) {
                const float wt = wv2p[(dh + 1) * 11 + dw + 5];
                #pragma unroll
                for (int i = 0; i < 16; ++i) acc[i] += wt * rb[i + dh - e + 8];
            }
        }
    }

    // ---- BN (inference) + sigmoid -> gate, stored back over LDS plane ----
    const float inv = bng[c] * rsqrtf(bnv[c] + BN_EPS);
    const float mu  = bnm[c];
    const float bt  = bnb[c];
    __syncthreads();   // all conv reads of sxp done before overwrite
    #pragma unroll
    for (int i = 0; i < 16; ++i) {
        const float att = (acc[i] - mu) * inv + bt;
        const float g   = 1.0f / (1.0f + __expf(-att));
        sxp[p + 6][q0 + i + 8] = g;
    }
    __syncthreads();

    // ---- Phase C: out = x * gate[i/3][j/3], float4 streaming ----
    const float4* __restrict__ x4 = (const float4*)xp;
    float4* __restrict__       o4 = (float4*)op;
    for (int k = 0; k < 36; ++k) {
        const int idx = tid + (k << 8);           // 0..9215 float4s
        const int row = idx / 48;                 // 192/4 = 48 float4 per row
        const int c4  = idx - row * 48;
        const float4 xv = x4[idx];
        const int gr = row / 3 + 6;
        const int jb = c4 * 4;
        float4 ov;
        ov.x = xv.x * sxp[gr][(jb    ) / 3 + 8];
        ov.y = xv.y * sxp[gr][(jb + 1) / 3 + 8];
        ov.z = xv.z * sxp[gr][(jb + 2) / 3 + 8];
        ov.w = xv.w * sxp[gr][(jb + 3) / 3 + 8];
        o4[idx] = ov;
    }
}

extern "C" void kernel_launch(void* const* d_in, const int* in_sizes, int n_in,
                              void* d_out, int out_size, void* d_ws, size_t ws_size,
                              hipStream_t stream) {
    const float* x   = (const float*)d_in[0];
    const float* wh1 = (const float*)d_in[1];
    const float* wv1 = (const float*)d_in[2];
    const float* wh2 = (const float*)d_in[3];
    const float* wv2 = (const float*)d_in[4];
    const float* g   = (const float*)d_in[5];
    const float* b   = (const float*)d_in[6];
    const float* m   = (const float*)d_in[7];
    const float* v   = (const float*)d_in[8];

    mra_fused<<<dim3(8 * 256), dim3(256), 0, stream>>>(
        x, wh1, wv1, wh2, wv2, g, b, m, v, (float*)d_out);
}

// Round 4
// 196.673 us; speedup vs baseline: 1.0011x; 1.0011x over previous
//
#include <hip/hip_runtime.h>
#include <math.h>

#define BN_EPS 1e-5f

__device__ __forceinline__ float max3f(float a, float b, float c) {
    return fmaxf(fmaxf(a, b), c);
}

// One block per (b,c) plane. 256 threads = 4 waves.
// Phase A: separable streaming blurpool(maxpool3x3(x)) -> sxp (64x64 @ offset [6][8])
// Phase B: four directional 33-tap convs from sxp
// Phase C: out = x * gate[i/3][j/3]
__global__ __launch_bounds__(256)
void mra_fused(const float* __restrict__ x,
               const float* __restrict__ wh1,
               const float* __restrict__ wv1,
               const float* __restrict__ wh2,
               const float* __restrict__ wv2,
               const float* __restrict__ bng,
               const float* __restrict__ bnb,
               const float* __restrict__ bnm,
               const float* __restrict__ bnv,
               float* __restrict__ out)
{
    __shared__ __align__(16) float sxp[76][84];     // 25.5 KB, zero halo
    __shared__ __align__(16) float rowbuf[4][192];  // per-wave hmax row buffer

    const int plane = blockIdx.x;       // b*256 + c
    const int c     = plane & 255;
    const int tid   = threadIdx.x;
    const int lane  = tid & 63;
    const int wv    = tid >> 6;
    const float* __restrict__ xp = x   + (size_t)plane * 36864;
    float* __restrict__       op = out + (size_t)plane * 36864;

    // ---- zero LDS (halo must be 0 for conv boundary) ----
    for (int i = tid; i < 76 * 84; i += 256) ((float*)sxp)[i] = 0.0f;
    __syncthreads();

    // ---- Phase A: streaming separable maxpool3x3(SAME) + blur4x4 stride-3 ----
    // wave wv owns output rows P0..P0+15 (P0=16*wv), lane owns output col q=lane.
    // hmax rows streamed: coalesced float4 load (48 lanes) -> reg hmax via shuffles
    // -> LDS row -> per-lane 4 stride-3 window values -> reg vertical max + blur.
    {
        const int P0 = wv << 4;
        float* rb = rowbuf[wv];
        const int i0 = (lane == 0) ? 1 : 3 * lane - 1;   // reflect: center col -1 == col 1
        const int i1 = 3 * lane, i2 = 3 * lane + 1, i3 = 3 * lane + 2;

        float h0[4], h1[4], h2[4];

        auto loadrow = [&](int r, float* dst) {
            r = r < 0 ? 0 : (r > 191 ? 191 : r);  // clamp == maxpool SAME semantics
            float4 v4 = make_float4(0.f, 0.f, 0.f, 0.f);
            if (lane < 48) v4 = *(const float4*)(xp + r * 192 + 4 * lane);
            float nl = __shfl_up(v4.w, 1);    // col 4l-1 from lane l-1
            float nr = __shfl_down(v4.x, 1);  // col 4l+4 from lane l+1
            if (lane == 0)  nl = v4.x;        // clamp left
            if (lane == 47) nr = v4.w;        // clamp right
            float4 hm;
            hm.x = max3f(nl,   v4.x, v4.y);
            hm.y = max3f(v4.x, v4.y, v4.z);
            hm.z = max3f(v4.y, v4.z, v4.w);
            hm.w = max3f(v4.z, v4.w, nr);
            if (lane < 48) *(float4*)(rb + 4 * lane) = hm;
            __builtin_amdgcn_wave_barrier();
            dst[0] = rb[i0]; dst[1] = rb[i1]; dst[2] = rb[i2]; dst[3] = rb[i3];
            __builtin_amdgcn_wave_barrier();
        };

        // blur-blend of vertical max3 over one center row
        auto emit = [&](const float* a, const float* b, const float* d) {
            return 0.125f * max3f(a[0], b[0], d[0])
                 + 0.375f * max3f(a[1], b[1], d[1])
                 + 0.375f * max3f(a[2], b[2], d[2])
                 + 0.125f * max3f(a[3], b[3], d[3]);
        };

        loadrow(3 * P0 - 2, h0);
        loadrow(3 * P0 - 1, h1);
        loadrow(3 * P0,     h2);
        float hbp = emit(h0, h1, h2);   // center row 3*P0-1

        #pragma unroll
        for (int i = 0; i < 16; ++i) {
            const int rbase = 3 * P0 + 3 * i;
            loadrow(rbase + 1, h0);
            const float hb0 = emit(h1, h2, h0);   // center 3p
            loadrow(rbase + 2, h1);
            const float hb1 = emit(h2, h0, h1);   // center 3p+1
            loadrow(rbase + 3, h2);
            const float hb2 = emit(h0, h1, h2);   // center 3p+2
            float a;
            if (i == 0 && wv == 0)   // top reflect: center -1 == center 1
                a = 0.375f * hb0 + 0.5f * hb1 + 0.125f * hb2;
            else
                a = 0.125f * hbp + 0.375f * hb0 + 0.375f * hb1 + 0.125f * hb2;
            hbp = hb2;
            sxp[P0 + i + 6][lane + 8] = a;
        }
    }
    __syncthreads();

    // ---- Phase B: four directional 33-tap depthwise convs ----
    // thread: output row p = tid>>2, horizontal strip q0..q0+15, q0 = 16*(tid&3)
    const int p  = tid >> 2;
    const int q0 = (tid & 3) << 4;
    float acc[16];
    #pragma unroll
    for (int i = 0; i < 16; ++i) acc[i] = 0.0f;

    const float* __restrict__ wh1p = wh1 + c * 33;
    const float* __restrict__ wv1p = wv1 + c * 33;
    const float* __restrict__ wh2p = wh2 + c * 33;
    const float* __restrict__ wv2p = wv2 + c * 33;

    #pragma unroll
    for (int e = -6; e <= 6; ++e) {
        // rowbuf rbx[j] = X(p+e, q0-8+j)   (LDS col index q0+j, halo gives zeros)
        float rbx[32];
        const float* rowl = &sxp[p + e + 6][q0];
        #pragma unroll
        for (int j4 = 0; j4 < 8; ++j4) {
            float4 v4 = *(const float4*)(rowl + 4 * j4);
            rbx[4 * j4 + 0] = v4.x; rbx[4 * j4 + 1] = v4.y;
            rbx[4 * j4 + 2] = v4.z; rbx[4 * j4 + 3] = v4.w;
        }
        if (e >= -5 && e <= 5) {
            #pragma unroll
            for (int dw = -1; dw <= 1; ++dw) {
                const float wt = wh1p[(e + 5) * 3 + dw + 1];
                #pragma unroll
                for (int i = 0; i < 16; ++i) acc[i] += wt * rbx[i + dw + 8];
            }
            #pragma unroll
            for (int dw = -1; dw <= 1; ++dw) {
                const float wt = wh2p[(e + 5) * 3 + dw + 1];
                #pragma unroll
                for (int i = 0; i < 16; ++i) acc[i] += wt * rbx[i + dw - e + 8];
            }
        }
        if (e >= -1 && e <= 1) {
            #pragma unroll
            for (int dw = -5; dw <= 5; ++dw) {
                const float wt = wv1p[(e + 1) * 11 + dw + 5];
                #pragma unroll
                for (int i = 0; i < 16; ++i) acc[i] += wt * rbx[i + dw + 8];
            }
        }
        #pragma unroll
        for (int dh = -1; dh <= 1; ++dh) {
            const int dw = dh - e;
            if (dw >= -5 && dw <= 5) {
                const float wt = wv2p[(dh + 1) * 11 + dw + 5];
                #pragma unroll
                for (int i = 0; i < 16; ++i) acc[i] += wt * rbx[i + dh - e + 8];
            }
        }
    }

    // ---- BN (inference) + sigmoid -> gate, stored back over LDS plane ----
    const float inv = bng[c] * rsqrtf(bnv[c] + BN_EPS);
    const float mu  = bnm[c];
    const float bt  = bnb[c];
    __syncthreads();   // all conv reads of sxp done before overwrite
    #pragma unroll
    for (int i = 0; i < 16; ++i) {
        const float att = (acc[i] - mu) * inv + bt;
        const float g   = 1.0f / (1.0f + __expf(-att));
        sxp[p + 6][q0 + i + 8] = g;
    }
    __syncthreads();

    // ---- Phase C: out = x * gate[i/3][j/3], float4 streaming ----
    const float4* __restrict__ x4 = (const float4*)xp;
    float4* __restrict__       o4 = (float4*)op;
    int rowj[3], gcj[3], rrj[3];
    #pragma unroll
    for (int j = 0; j < 3; ++j) {
        const int idx0 = tid + (j << 8);
        const int rw   = idx0 / 48;            // 192/4=48 float4 per row
        const int c4   = idx0 - rw * 48;
        rowj[j] = rw;
        const int jb = c4 << 2;
        gcj[j] = jb / 3;
        rrj[j] = jb - 3 * gcj[j];
    }
    #pragma unroll
    for (int m = 0; m < 12; ++m) {
        #pragma unroll
        for (int j = 0; j < 3; ++j) {
            const int row = rowj[j] + (m << 4);
            const int idx = tid + ((m * 3 + j) << 8);
            const int gr  = row / 3 + 6;
            const float g0 = sxp[gr][gcj[j] + 8];
            const float g1 = sxp[gr][gcj[j] + 9];
            const float4 xv = x4[idx];
            float4 ov;
            const float s1 = (rrj[j] == 2) ? g1 : g0;
            const float s2 = (rrj[j] >= 1) ? g1 : g0;
            ov.x = xv.x * g0;
            ov.y = xv.y * s1;
            ov.z = xv.z * s2;
            ov.w = xv.w * g1;
            o4[idx] = ov;
        }
    }
}

extern "C" void kernel_launch(void* const* d_in, const int* in_sizes, int n_in,
                              void* d_out, int out_size, void* d_ws, size_t ws_size,
                              hipStream_t stream) {
    const float* x   = (const float*)d_in[0];
    const float* wh1 = (const float*)d_in[1];
    const float* wv1 = (const float*)d_in[2];
    const float* wh2 = (const float*)d_in[3];
    const float* wv2 = (const float*)d_in[4];
    const float* g   = (const float*)d_in[5];
    const float* b   = (const float*)d_in[6];
    const float* m   = (const float*)d_in[7];
    const float* v   = (const float*)d_in[8];

    mra_fused<<<dim3(8 * 256), dim3(256), 0, stream>>>(
        x, wh1, wv1, wh2, wv2, g, b, m, v, (float*)d_out);
}

// Round 5
// 175.072 us; speedup vs baseline: 1.1246x; 1.1234x over previous
//
#include <hip/hip_runtime.h>
#include <hip/hip_fp16.h>
#include <math.h>

#define BN_EPS 1e-5f

__device__ __forceinline__ float max3f(float a, float b, float c) {
    return fmaxf(fmaxf(a, b), c);
}

// One block per (b,c) plane. 256 threads = 4 waves. 8 blocks/CU resident (full GPU).
// Phase A: streaming separable blurpool(maxpool3x3(x)) with 4-deep global prefetch ring
//          -> fp16 plane sxp_h (64x64 @ offset [6][8], zero halo)
// Phase B: four directional 33-tap convs (fp16 LDS reads, f32 accumulate)
// Phase C: out = x * gate[i/3][j/3]
__global__ __launch_bounds__(256, 8)
void mra_fused(const float* __restrict__ x,
               const float* __restrict__ wh1,
               const float* __restrict__ wv1,
               const float* __restrict__ wh2,
               const float* __restrict__ wv2,
               const float* __restrict__ bng,
               const float* __restrict__ bnb,
               const float* __restrict__ bnm,
               const float* __restrict__ bnv,
               float* __restrict__ out)
{
    __shared__ __align__(16) __half sxp_h[76][84];     // 12.77 KB, zero halo
    __shared__ __align__(16) float  rowbuf[4][2][192]; // 6 KB, per-wave double buffer

    const int plane = blockIdx.x;       // b*256 + c
    const int c     = plane & 255;
    const int tid   = threadIdx.x;
    const int lane  = tid & 63;
    const int wv    = tid >> 6;
    const float* __restrict__ xp = x   + (size_t)plane * 36864;
    float* __restrict__       op = out + (size_t)plane * 36864;

    // ---- zero fp16 plane (halo must be 0 for conv boundary) ----
    {
        int* z = (int*)&sxp_h[0][0];
        #pragma unroll
        for (int i = 0; i < 13; ++i) {
            const int idx = tid + (i << 8);
            if (idx < (76 * 84 * 2) / 4) z[idx] = 0;
        }
    }
    __syncthreads();

    // ---- Phase A: streaming maxpool3x3(SAME) + blur4x4 stride-3 ----
    // wave wv owns output rows P0..P0+15; lane owns output col q=lane.
    // 51 source rows streamed with a 4-deep float4 prefetch ring (loads issued
    // in source order BEFORE the wave_barrier fences -> latency overlapped).
    {
        const int P0 = wv << 4;
        float* rb0 = rowbuf[wv][0];
        float* rb1 = rowbuf[wv][1];
        const int i0 = (lane == 0) ? 1 : 3 * lane - 1;  // reflect: col -1 == col 1
        const int i1 = 3 * lane, i2 = 3 * lane + 1, i3 = 3 * lane + 2;
        const int r0 = 3 * P0 - 2;

        float4 ring[4];
        auto issue = [&](int k, float4* slot) {
            int r = r0 + k;
            r = r < 0 ? 0 : (r > 191 ? 191 : r);   // clamp == maxpool SAME
            float4 v = make_float4(0.f, 0.f, 0.f, 0.f);
            if (lane < 48) v = *(const float4*)(xp + r * 192 + 4 * lane);
            *slot = v;
        };
        issue(0, &ring[0]); issue(1, &ring[1]);
        issue(2, &ring[2]); issue(3, &ring[3]);

        float h[3][4];     // hmax history of last 3 source rows
        float hb[3];       // blur-row values for current output row
        float hbp = 0.f;   // previous blur-row (center 3p-1)

        #pragma unroll
        for (int k = 0; k < 51; ++k) {
            float4 v4 = ring[k & 3];               // vmcnt wait lands here
            if (k + 4 < 51) issue(k + 4, &ring[k & 3]);

            float nl = __shfl_up(v4.w, 1);
            float nr = __shfl_down(v4.x, 1);
            if (lane == 0)  nl = v4.x;
            if (lane == 47) nr = v4.w;
            float* rb = (k & 1) ? rb1 : rb0;
            if (lane < 48) {
                float4 hm;
                hm.x = max3f(nl,   v4.x, v4.y);
                hm.y = max3f(v4.x, v4.y, v4.z);
                hm.z = max3f(v4.y, v4.z, v4.w);
                hm.w = max3f(v4.z, v4.w, nr);
                *(float4*)(rb + 4 * lane) = hm;
            }
            __builtin_amdgcn_wave_barrier();
            float* hk = h[k % 3];
            hk[0] = rb[i0]; hk[1] = rb[i1]; hk[2] = rb[i2]; hk[3] = rb[i3];
            __builtin_amdgcn_wave_barrier();

            if (k >= 2) {
                const float* a = h[(k - 2) % 3];
                const float* b = h[(k - 1) % 3];
                const float* d = h[k % 3];
                const float e4 =
                      0.125f * max3f(a[0], b[0], d[0])
                    + 0.375f * max3f(a[1], b[1], d[1])
                    + 0.375f * max3f(a[2], b[2], d[2])
                    + 0.125f * max3f(a[3], b[3], d[3]);
                if (k == 2) {
                    hbp = e4;                       // center row 3*P0-1
                } else {
                    hb[k % 3] = e4;                 // k%3: 0->hb0, 1->hb1, 2->hb2
                    if (k % 3 == 2) {
                        const int i = (k - 5) / 3;  // output row P0+i
                        float a_out;
                        if (i == 0 && wv == 0)      // top reflect: center -1 == 1
                            a_out = 0.375f * hb[0] + 0.5f * hb[1] + 0.125f * hb[2];
                        else
                            a_out = 0.125f * hbp + 0.375f * hb[0]
                                  + 0.375f * hb[1] + 0.125f * hb[2];
                        hbp = hb[2];
                        sxp_h[P0 + i + 6][lane + 8] = __float2half(a_out);
                    }
                }
            }
        }
    }
    __syncthreads();

    // ---- Phase B: four directional 33-tap depthwise convs ----
    // thread: output row p = tid>>2, horizontal strip q0..q0+15, q0 = 16*(tid&3)
    const int p  = tid >> 2;
    const int q0 = (tid & 3) << 4;
    float acc[16];
    #pragma unroll
    for (int i = 0; i < 16; ++i) acc[i] = 0.0f;

    const float* __restrict__ wh1p = wh1 + c * 33;
    const float* __restrict__ wv1p = wv1 + c * 33;
    const float* __restrict__ wh2p = wh2 + c * 33;
    const float* __restrict__ wv2p = wv2 + c * 33;

    #pragma unroll
    for (int e = -6; e <= 6; ++e) {
        // rbx[j] = X(p+e, q0-8+j); storage col q0+j (halo gives zeros).
        // only j in [2,29] is ever used; the rest DCE away.
        float rbx[32];
        const __half* rowl = &sxp_h[p + e + 6][q0];
        #pragma unroll
        for (int u = 0; u < 8; ++u) {
            const __half2* h2p = (const __half2*)(rowl + 4 * u);
            const float2 f0 = __half22float2(h2p[0]);
            const float2 f1 = __half22float2(h2p[1]);
            rbx[4 * u + 0] = f0.x; rbx[4 * u + 1] = f0.y;
            rbx[4 * u + 2] = f1.x; rbx[4 * u + 3] = f1.y;
        }
        if (e >= -5 && e <= 5) {
            #pragma unroll
            for (int dw = -1; dw <= 1; ++dw) {
                const float wt = wh1p[(e + 5) * 3 + dw + 1];
                #pragma unroll
                for (int i = 0; i < 16; ++i) acc[i] += wt * rbx[i + dw + 8];
            }
            #pragma unroll
            for (int dw = -1; dw <= 1; ++dw) {
                const float wt = wh2p[(e + 5) * 3 + dw + 1];
                #pragma unroll
                for (int i = 0; i < 16; ++i) acc[i] += wt * rbx[i + dw - e + 8];
            }
        }
        if (e >= -1 && e <= 1) {
            #pragma unroll
            for (int dw = -5; dw <= 5; ++dw) {
                const float wt = wv1p[(e + 1) * 11 + dw + 5];
                #pragma unroll
                for (int i = 0; i < 16; ++i) acc[i] += wt * rbx[i + dw + 8];
            }
        }
        #pragma unroll
        for (int dh = -1; dh <= 1; ++dh) {
            const int dw = dh - e;
            if (dw >= -5 && dw <= 5) {
                const float wt = wv2p[(dh + 1) * 11 + dw + 5];
                #pragma unroll
                for (int i = 0; i < 16; ++i) acc[i] += wt * rbx[i + dh - e + 8];
            }
        }
    }

    // ---- BN (inference) + sigmoid -> gate, stored back over LDS plane (fp16) ----
    const float inv = bng[c] * rsqrtf(bnv[c] + BN_EPS);
    const float mu  = bnm[c];
    const float bt  = bnb[c];
    __syncthreads();   // all conv reads of sxp_h done before overwrite
    #pragma unroll
    for (int i = 0; i < 8; ++i) {
        const float a0 = (acc[2 * i]     - mu) * inv + bt;
        const float a1 = (acc[2 * i + 1] - mu) * inv + bt;
        const float g0 = 1.0f / (1.0f + __expf(-a0));
        const float g1 = 1.0f / (1.0f + __expf(-a1));
        *(__half2*)(&sxp_h[p + 6][q0 + 2 * i + 8]) = __floats2half2_rn(g0, g1);
    }
    __syncthreads();

    // ---- Phase C: out = x * gate[i/3][j/3], float4 streaming ----
    const float4* __restrict__ x4 = (const float4*)xp;
    float4* __restrict__       o4 = (float4*)op;
    int rowj[3], gcj[3], rrj[3];
    #pragma unroll
    for (int j = 0; j < 3; ++j) {
        const int idx0 = tid + (j << 8);
        const int rw   = idx0 / 48;            // 192/4=48 float4 per row
        const int c4   = idx0 - rw * 48;
        rowj[j] = rw;
        const int jb = c4 << 2;
        gcj[j] = jb / 3;
        rrj[j] = jb - 3 * gcj[j];
    }
    #pragma unroll
    for (int m = 0; m < 12; ++m) {
        #pragma unroll
        for (int j = 0; j < 3; ++j) {
            const int row = rowj[j] + (m << 4);
            const int idx = tid + ((m * 3 + j) << 8);
            const int gr  = row / 3 + 6;
            const float g0 = __half2float(sxp_h[gr][gcj[j] + 8]);
            const float g1 = __half2float(sxp_h[gr][gcj[j] + 9]);
            const float4 xv = x4[idx];
            float4 ov;
            const float s1 = (rrj[j] == 2) ? g1 : g0;
            const float s2 = (rrj[j] >= 1) ? g1 : g0;
            ov.x = xv.x * g0;
            ov.y = xv.y * s1;
            ov.z = xv.z * s2;
            ov.w = xv.w * g1;
            o4[idx] = ov;
        }
    }
}

extern "C" void kernel_launch(void* const* d_in, const int* in_sizes, int n_in,
                              void* d_out, int out_size, void* d_ws, size_t ws_size,
                              hipStream_t stream) {
    const float* x   = (const float*)d_in[0];
    const float* wh1 = (const float*)d_in[1];
    const float* wv1 = (const float*)d_in[2];
    const float* wh2 = (const float*)d_in[3];
    const float* wv2 = (const float*)d_in[4];
    const float* g   = (const float*)d_in[5];
    const float* b   = (const float*)d_in[6];
    const float* m   = (const float*)d_in[7];
    const float* v   = (const float*)d_in[8];

    mra_fused<<<dim3(8 * 256), dim3(256), 0, stream>>>(
        x, wh1, wv1, wh2, wv2, g, b, m, v, (float*)d_out);
}